// Round 1
// baseline (679.305 us; speedup 1.0000x reference)
//
#include <hip/hip_runtime.h>
#include <math.h>

#define EPSV 1e-5f

// ---------------------------------------------------------------- constants
// cos/sin(2*pi*j/32), j=0..31 (compile-time folded into FMA literals)
constexpr float COS32[32] = {
     1.00000000f,  0.98078528f,  0.92387953f,  0.83146961f,
     0.70710678f,  0.55557023f,  0.38268343f,  0.19509032f,
     0.00000000f, -0.19509032f, -0.38268343f, -0.55557023f,
    -0.70710678f, -0.83146961f, -0.92387953f, -0.98078528f,
    -1.00000000f, -0.98078528f, -0.92387953f, -0.83146961f,
    -0.70710678f, -0.55557023f, -0.38268343f, -0.19509032f,
     0.00000000f,  0.19509032f,  0.38268343f,  0.55557023f,
     0.70710678f,  0.83146961f,  0.92387953f,  0.98078528f };
constexpr float SIN32[32] = {
     0.00000000f,  0.19509032f,  0.38268343f,  0.55557023f,
     0.70710678f,  0.83146961f,  0.92387953f,  0.98078528f,
     1.00000000f,  0.98078528f,  0.92387953f,  0.83146961f,
     0.70710678f,  0.55557023f,  0.38268343f,  0.19509032f,
     0.00000000f, -0.19509032f, -0.38268343f, -0.55557023f,
    -0.70710678f, -0.83146961f, -0.92387953f, -0.98078528f,
    -1.00000000f, -0.98078528f, -0.92387953f, -0.83146961f,
    -0.70710678f, -0.55557023f, -0.38268343f, -0.19509032f };

__device__ __forceinline__ float geluf(float x) {
    float x3 = x * x * x;
    return 0.5f * x * (1.f + tanhf(0.7978845608028654f * (x + 0.044715f * x3)));
}

// ------------------------------------------------ Kernel A: time-LN + scan
// grid = B*H*W = 4096 blocks, 128 threads (one per d). Emits buf1 = y + res
// in [BT, HW, D] layout and h_out.
__global__ __launch_bounds__(128) void k_time_scan(
    const float* __restrict__ x, const float* __restrict__ dt,
    const float* __restrict__ lng, const float* __restrict__ lnb,
    const float* __restrict__ om, const float* __restrict__ bin,
    const float* __restrict__ hcr, const float* __restrict__ hci,
    const float* __restrict__ hd, float* __restrict__ buf1,
    float* __restrict__ hout)
{
    const int blk = blockIdx.x;          // b*1024 + h*32 + w
    const int b = blk >> 10;
    const int hw = blk & 1023;
    const int d = threadIdx.x;
    const float gd = lng[d], bd = lnb[d];
    const float omd = om[d], bind = bin[d];
    const float crd = hcr[d], cid = hci[d], dhd = hd[d];
    float hr = 0.f, hi = 0.f;
    __shared__ float red[4];
    const int wave = d >> 6;
    for (int t = 0; t < 16; ++t) {
        const size_t base = ((size_t)(b * 16 + t) * 1024 + hw) * 128;
        const float v = x[base + d];
        float s1 = v, s2 = v * v;
        #pragma unroll
        for (int o = 32; o > 0; o >>= 1) {
            s1 += __shfl_xor(s1, o);
            s2 += __shfl_xor(s2, o);
        }
        if ((d & 63) == 0) { red[wave * 2] = s1; red[wave * 2 + 1] = s2; }
        __syncthreads();
        const float mu  = (red[0] + red[2]) * (1.f / 128.f);
        const float var = (red[1] + red[3]) * (1.f / 128.f) - mu * mu;
        const float rv  = rsqrtf(var + EPSV);
        const float xt  = (v - mu) * rv * gd + bd;
        const float dtt = dt[b * 16 + t];
        float pi_, pr_;
        __sincosf(omd * dtt, &pi_, &pr_);
        const float nhr = pr_ * hr - pi_ * hi + bind * xt;
        const float nhi = pr_ * hi + pi_ * hr;
        hr = nhr; hi = nhi;
        buf1[base + d] = crd * hr - cid * hi + dhd * xt + v;
        __syncthreads();
    }
    const size_t ho = ((size_t)blk * 128 + d) * 2;
    hout[ho] = hr; hout[ho + 1] = hi;
}

// --------------------------------------- Kernel B: space-LN + NHWD -> NDHW
// grid = BT*H = 2048, block 256.
__global__ __launch_bounds__(256) void k_space_ln(
    const float* __restrict__ buf1, const float* __restrict__ lng,
    const float* __restrict__ lnb, float* __restrict__ xr)
{
    const int n = blockIdx.x >> 5, h = blockIdx.x & 31;
    __shared__ float ld[128][33];
    const int tid = threadIdx.x;
    const int w = tid >> 3, d0 = (tid & 7) << 4;
    const float* src = buf1 + ((size_t)(n * 1024 + h * 32 + w) * 128 + d0);
    float v[16];
    #pragma unroll
    for (int i = 0; i < 4; ++i) {
        float4 t = ((const float4*)src)[i];
        v[4*i] = t.x; v[4*i+1] = t.y; v[4*i+2] = t.z; v[4*i+3] = t.w;
    }
    float s1 = 0.f, s2 = 0.f;
    #pragma unroll
    for (int i = 0; i < 16; ++i) { s1 += v[i]; s2 += v[i] * v[i]; }
    s1 += __shfl_xor(s1, 1); s2 += __shfl_xor(s2, 1);
    s1 += __shfl_xor(s1, 2); s2 += __shfl_xor(s2, 2);
    s1 += __shfl_xor(s1, 4); s2 += __shfl_xor(s2, 4);
    const float mu = s1 * (1.f / 128.f);
    const float rv = rsqrtf(s2 * (1.f / 128.f) - mu * mu + EPSV);
    #pragma unroll
    for (int i = 0; i < 16; ++i)
        ld[d0 + i][w] = (v[i] - mu) * rv * lng[d0 + i] + lnb[d0 + i];
    __syncthreads();
    const int dd = tid >> 1, w0 = (tid & 1) << 4;
    float* dst = xr + (((size_t)n * 128 + dd) * 32 + h) * 32 + w0;
    #pragma unroll
    for (int i = 0; i < 16; ++i) dst[i] = ld[dd][w0 + i];
}

// --------------------------- Kernel C: precompute K = U@V and mod = exp(lam*dt)
__global__ __launch_bounds__(256) void k_pre(
    const float* __restrict__ ur, const float* __restrict__ ui,
    const float* __restrict__ vr, const float* __restrict__ vi,
    const float* __restrict__ dec, const float* __restrict__ om,
    const float* __restrict__ dt, float* __restrict__ Kb, float* __restrict__ Mb)
{
    const int id = blockIdx.x * 256 + threadIdx.x;
    if (id < 128 * 17) {
        const int d = id / 17, f = id % 17;
        float ar = 0.f, ai = 0.f;
        for (int r = 0; r < 32; ++r) {
            const float a = ur[d * 32 + r], b = ui[d * 32 + r];
            const float c = vr[r * 17 + f], e = vi[r * 17 + f];
            ar += a * c - b * e;
            ai += a * e + b * c;
        }
        Kb[id * 2] = ar; Kb[id * 2 + 1] = ai;
    } else if (id < 128 * 17 + 64 * 17) {
        const int m = id - 128 * 17;
        const int n = m / 17, f = m % 17;
        const float xv = dec[f];
        const float sp = (xv > 20.f) ? xv : log1pf(expf(xv));
        const float dtv = dt[n];
        const float mag = expf(-sp * dtv);
        float s, c; __sincosf(om[f] * dtv, &s, &c);
        Mb[m * 2] = mag * c; Mb[m * 2 + 1] = mag * s;
    }
}

// ------------------------------------------- Kernel D: complex 3x3 conv SAME
// grid = BT*C = 4096 (n = blk>>6, co = blk&63), block 256, 4 px/thread.
__global__ __launch_bounds__(256) void k_conv(
    const float* __restrict__ xr, const float* __restrict__ cwr,
    const float* __restrict__ cwi, const float* __restrict__ cbr,
    const float* __restrict__ cbi, float* __restrict__ xcs)
{
    const int n = blockIdx.x >> 6, co = blockIdx.x & 63;
    __shared__ float as_[34 * 34];
    __shared__ float bs_[34 * 34];
    const int tid = threadIdx.x;
    for (int i = tid; i < 34 * 34; i += 256) { as_[i] = 0.f; bs_[i] = 0.f; }
    const int p0 = tid << 2;
    const int ph = p0 >> 5, pw = p0 & 31;
    float accr[4] = {0.f, 0.f, 0.f, 0.f}, acci[4] = {0.f, 0.f, 0.f, 0.f};
    const float* wrp = cwr + (size_t)co * 64 * 9;
    const float* wip = cwi + (size_t)co * 64 * 9;
    const float* base = xr + (size_t)n * 128 * 1024;
    const int lb = (ph + 1) * 34 + pw + 1;
    for (int ci = 0; ci < 64; ++ci) {
        __syncthreads();   // protect LDS (also separates zero-init at ci=0)
        const float4 av = *(const float4*)(base + (size_t)(2 * ci) * 1024 + p0);
        const float4 bv = *(const float4*)(base + (size_t)(2 * ci + 1) * 1024 + p0);
        as_[lb + 0] = av.x; as_[lb + 1] = av.y; as_[lb + 2] = av.z; as_[lb + 3] = av.w;
        bs_[lb + 0] = bv.x; bs_[lb + 1] = bv.y; bs_[lb + 2] = bv.z; bs_[lb + 3] = bv.w;
        __syncthreads();
        float w_r[9], w_i[9];
        #pragma unroll
        for (int k = 0; k < 9; ++k) { w_r[k] = wrp[ci * 9 + k]; w_i[k] = wip[ci * 9 + k]; }
        #pragma unroll
        for (int dy = 0; dy < 3; ++dy) {
            const float* arow = &as_[(ph + dy) * 34 + pw];
            const float* brow = &bs_[(ph + dy) * 34 + pw];
            float a6[6], b6[6];
            #pragma unroll
            for (int j = 0; j < 6; ++j) { a6[j] = arow[j]; b6[j] = brow[j]; }
            #pragma unroll
            for (int dx = 0; dx < 3; ++dx) {
                const float wrk = w_r[dy * 3 + dx], wik = w_i[dy * 3 + dx];
                #pragma unroll
                for (int j = 0; j < 4; ++j) {
                    accr[j] = fmaf(a6[dx + j], wrk, fmaf(-b6[dx + j], wik, accr[j]));
                    acci[j] = fmaf(a6[dx + j], wik, fmaf( b6[dx + j], wrk, acci[j]));
                }
            }
        }
    }
    const float brv = cbr[co], biv = cbi[co];
    float* outr = xcs + ((size_t)n * 128 + 2 * co) * 1024 + p0;
    float* outi = outr + 1024;
    #pragma unroll
    for (int j = 0; j < 4; ++j) { outr[j] = accr[j] + brv; outi[j] = acci[j] + biv; }
}

// ------------------------------------- Kernel E: rfft*K*mod -> irfft, += xcs
// one thread per (n,d,h) row; grid 1024 x 256.
__global__ __launch_bounds__(256) void k_spec(
    const float* __restrict__ xr, const float* __restrict__ Kb,
    const float* __restrict__ Mb, float* __restrict__ xcs)
{
    const int row = blockIdx.x * 256 + threadIdx.x;   // < 64*128*32
    const int n = row >> 12;
    const int d = (row >> 5) & 127;
    const float* src = xr + (size_t)row * 32;
    float xv[32];
    #pragma unroll
    for (int i = 0; i < 8; ++i) {
        float4 t = ((const float4*)src)[i];
        xv[4*i] = t.x; xv[4*i+1] = t.y; xv[4*i+2] = t.z; xv[4*i+3] = t.w;
    }
    float zr[17], zi[17];
    #pragma unroll
    for (int f = 0; f < 17; ++f) {
        float sr = 0.f, si = 0.f;
        #pragma unroll
        for (int w2 = 0; w2 < 32; ++w2) {
            sr += xv[w2] * COS32[(f * w2) & 31];
            si -= xv[w2] * SIN32[(f * w2) & 31];
        }
        const float kr = Kb[(d * 17 + f) * 2], ki = Kb[(d * 17 + f) * 2 + 1];
        const float mr = Mb[(n * 17 + f) * 2], mi = Mb[(n * 17 + f) * 2 + 1];
        const float cr2 = kr * mr - ki * mi;
        const float ci2 = kr * mi + ki * mr;
        zr[f] = sr * cr2 - si * ci2;
        zi[f] = sr * ci2 + si * cr2;
    }
    float* dst = xcs + (size_t)row * 32;
    #pragma unroll
    for (int w2 = 0; w2 < 32; ++w2) {
        float acc = zr[0] + ((w2 & 1) ? -zr[16] : zr[16]);
        #pragma unroll
        for (int f = 1; f < 16; ++f)
            acc += 2.f * (zr[f] * COS32[(f * w2) & 31] - zi[f] * SIN32[(f * w2) & 31]);
        dst[w2] += acc * (1.f / 32.f);
    }
}

// --------------------- Kernel F: residual combine + feat-LN (NDHW -> NHWD)
// buf1 updated in place to hold res; xn gets normalized features.
__global__ __launch_bounds__(256) void k_combine(
    const float* __restrict__ xcs, float* __restrict__ buf1,
    const float* __restrict__ lng, const float* __restrict__ lnb,
    float* __restrict__ xn)
{
    const int n = blockIdx.x >> 5, h = blockIdx.x & 31;
    __shared__ float ld[128][33];
    const int tid = threadIdx.x;
    {
        const int dd = tid >> 1, w0 = (tid & 1) << 4;
        const float* src = xcs + (((size_t)n * 128 + dd) * 32 + h) * 32 + w0;
        #pragma unroll
        for (int i = 0; i < 16; i += 4) {
            float4 t = *(const float4*)(src + i);
            ld[dd][w0+i] = t.x; ld[dd][w0+i+1] = t.y; ld[dd][w0+i+2] = t.z; ld[dd][w0+i+3] = t.w;
        }
    }
    __syncthreads();
    const int w = tid >> 3, d0 = (tid & 7) << 4;
    float* bp = buf1 + ((size_t)(n * 1024 + h * 32 + w) * 128 + d0);
    float v[16];
    #pragma unroll
    for (int i = 0; i < 4; ++i) {
        float4 t = ((const float4*)bp)[i];
        v[4*i] = t.x; v[4*i+1] = t.y; v[4*i+2] = t.z; v[4*i+3] = t.w;
    }
    float s1 = 0.f, s2 = 0.f;
    #pragma unroll
    for (int i = 0; i < 16; ++i) {
        v[i] += ld[d0 + i][w];
        s1 += v[i]; s2 += v[i] * v[i];
    }
    s1 += __shfl_xor(s1, 1); s2 += __shfl_xor(s2, 1);
    s1 += __shfl_xor(s1, 2); s2 += __shfl_xor(s2, 2);
    s1 += __shfl_xor(s1, 4); s2 += __shfl_xor(s2, 4);
    const float mu = s1 * (1.f / 128.f);
    const float rv = rsqrtf(s2 * (1.f / 128.f) - mu * mu + EPSV);
    #pragma unroll
    for (int i = 0; i < 4; ++i)
        ((float4*)bp)[i] = make_float4(v[4*i], v[4*i+1], v[4*i+2], v[4*i+3]);
    float* xp = xn + ((size_t)(n * 1024 + h * 32 + w) * 128 + d0);
    #pragma unroll
    for (int i = 0; i < 16; ++i)
        xp[i] = (v[i] - mu) * rv * lng[d0 + i] + lnb[d0 + i];
}

// -------------------------------- Kernel G: complex MLP 64->256->64 + res
// block = 16 positions, 256 threads; grid 4096.
__global__ __launch_bounds__(256) void k_mlp(
    const float* __restrict__ xn, const float* __restrict__ res,
    const float* __restrict__ w1r, const float* __restrict__ w1i,
    const float* __restrict__ b1r, const float* __restrict__ b1i,
    const float* __restrict__ w2r, const float* __restrict__ w2i,
    const float* __restrict__ b2r, const float* __restrict__ b2i,
    float* __restrict__ outp)
{
    const int m0 = blockIdx.x * 16;
    __shared__ float xs[16 * 128];
    __shared__ float hs[16 * 512];
    const int tid = threadIdx.x;
    {
        const float4* s4 = (const float4*)(xn + (size_t)m0 * 128);
        float4* d4 = (float4*)xs;
        d4[tid] = s4[tid];
        d4[tid + 256] = s4[tid + 256];
    }
    __syncthreads();
    // GEMM1: e = tid
    float hrA[16], hiA[16];
    {
        const float br_ = b1r[tid], bi_ = b1i[tid];
        #pragma unroll
        for (int m = 0; m < 16; ++m) { hrA[m] = br_; hiA[m] = bi_; }
    }
    const float2* xs2 = (const float2*)xs;
    for (int c = 0; c < 64; ++c) {
        const float wr_ = w1r[c * 256 + tid], wi_ = w1i[c * 256 + tid];
        #pragma unroll
        for (int m = 0; m < 16; ++m) {
            const float2 xv = xs2[m * 64 + c];
            hrA[m] = fmaf(xv.x, wr_, fmaf(-xv.y, wi_, hrA[m]));
            hiA[m] = fmaf(xv.x, wi_, fmaf( xv.y, wr_, hiA[m]));
        }
    }
    float2* hs2 = (float2*)hs;
    #pragma unroll
    for (int m = 0; m < 16; ++m)
        hs2[m * 256 + tid] = make_float2(geluf(hrA[m]), geluf(hiA[m]));
    __syncthreads();
    // GEMM2: co = tid&63, 4 m's per thread
    const int co = tid & 63, mg = tid >> 6;
    float orA[4], oiA[4];
    {
        const float br_ = b2r[co], bi_ = b2i[co];
        #pragma unroll
        for (int k = 0; k < 4; ++k) { orA[k] = br_; oiA[k] = bi_; }
    }
    for (int e = 0; e < 256; ++e) {
        const float wr_ = w2r[e * 64 + co], wi_ = w2i[e * 64 + co];
        #pragma unroll
        for (int k = 0; k < 4; ++k) {
            const float2 hv = hs2[(mg * 4 + k) * 256 + e];
            orA[k] = fmaf(hv.x, wr_, fmaf(-hv.y, wi_, orA[k]));
            oiA[k] = fmaf(hv.x, wi_, fmaf( hv.y, wr_, oiA[k]));
        }
    }
    #pragma unroll
    for (int k = 0; k < 4; ++k) {
        const size_t o = ((size_t)(m0 + mg * 4 + k)) * 128 + 2 * co;
        const float2 r = *(const float2*)(res + o);
        *(float2*)(outp + o) = make_float2(orA[k] + r.x, oiA[k] + r.y);
    }
}

extern "C" void kernel_launch(void* const* d_in, const int* in_sizes, int n_in,
                              void* d_out, int out_size, void* d_ws, size_t ws_size,
                              hipStream_t stream) {
    const float* x          = (const float*)d_in[0];
    const float* dt         = (const float*)d_in[1];
    const float* ln_time_g  = (const float*)d_in[2];
    const float* ln_time_b  = (const float*)d_in[3];
    const float* ln_space_g = (const float*)d_in[4];
    const float* ln_space_b = (const float*)d_in[5];
    const float* ln_feat_g  = (const float*)d_in[6];
    const float* ln_feat_b  = (const float*)d_in[7];
    const float* ham_omega  = (const float*)d_in[8];
    const float* ham_bin    = (const float*)d_in[9];
    const float* ham_cr     = (const float*)d_in[10];
    const float* ham_ci     = (const float*)d_in[11];
    const float* ham_d      = (const float*)d_in[12];
    const float* cliff_wr   = (const float*)d_in[13];
    const float* cliff_wi   = (const float*)d_in[14];
    const float* cliff_br   = (const float*)d_in[15];
    const float* cliff_bi   = (const float*)d_in[16];
    const float* spec_ur    = (const float*)d_in[17];
    const float* spec_ui    = (const float*)d_in[18];
    const float* spec_vr    = (const float*)d_in[19];
    const float* spec_vi    = (const float*)d_in[20];
    const float* spec_decay = (const float*)d_in[21];
    const float* spec_omega = (const float*)d_in[22];
    const float* w1r        = (const float*)d_in[23];
    const float* w1i        = (const float*)d_in[24];
    const float* b1r        = (const float*)d_in[25];
    const float* b1i        = (const float*)d_in[26];
    const float* w2r        = (const float*)d_in[27];
    const float* w2i        = (const float*)d_in[28];
    const float* b2r        = (const float*)d_in[29];
    const float* b2i        = (const float*)d_in[30];

    float* out = (float*)d_out;
    const size_t NX = 8388608;           // B*T*H*W*C*2
    float* hout = out + NX;              // h_out region
    float* xcs  = out;                   // conv+spec accumulator reuses x_out region
    float* ws   = (float*)d_ws;
    float* buf1 = ws;                    // [BT*HW, 128] residual/stage buffer
    float* xr   = ws + NX;               // [BT, 128, 32, 32]
    float* Kb   = ws + 2 * NX;           // 128*17 complex
    float* Mb   = Kb + 2176 * 2;         // 64*17 complex
    float* xn   = xr;                    // alias: xr dead after k_spec

    k_pre<<<13, 256, 0, stream>>>(spec_ur, spec_ui, spec_vr, spec_vi,
                                  spec_decay, spec_omega, dt, Kb, Mb);
    k_time_scan<<<4096, 128, 0, stream>>>(x, dt, ln_time_g, ln_time_b,
                                          ham_omega, ham_bin, ham_cr, ham_ci,
                                          ham_d, buf1, hout);
    k_space_ln<<<2048, 256, 0, stream>>>(buf1, ln_space_g, ln_space_b, xr);
    k_conv<<<4096, 256, 0, stream>>>(xr, cliff_wr, cliff_wi, cliff_br, cliff_bi, xcs);
    k_spec<<<1024, 256, 0, stream>>>(xr, Kb, Mb, xcs);
    k_combine<<<2048, 256, 0, stream>>>(xcs, buf1, ln_feat_g, ln_feat_b, xn);
    k_mlp<<<4096, 256, 0, stream>>>(xn, buf1, w1r, w1i, b1r, b1i,
                                    w2r, w2i, b2r, b2i, out);
}

// Round 2
// 174.674 us; speedup vs baseline: 3.8890x; 3.8890x over previous
//
#include <hip/hip_runtime.h>
#include <math.h>

#define EPSV 1e-5f

typedef short bfx8 __attribute__((ext_vector_type(8)));
typedef float fx4  __attribute__((ext_vector_type(4)));

// cos/sin(2*pi*j/32)
constexpr float COS32[32] = {
     1.00000000f,  0.98078528f,  0.92387953f,  0.83146961f,
     0.70710678f,  0.55557023f,  0.38268343f,  0.19509032f,
     0.00000000f, -0.19509032f, -0.38268343f, -0.55557023f,
    -0.70710678f, -0.83146961f, -0.92387953f, -0.98078528f,
    -1.00000000f, -0.98078528f, -0.92387953f, -0.83146961f,
    -0.70710678f, -0.55557023f, -0.38268343f, -0.19509032f,
     0.00000000f,  0.19509032f,  0.38268343f,  0.55557023f,
     0.70710678f,  0.83146961f,  0.92387953f,  0.98078528f };
constexpr float SIN32[32] = {
     0.00000000f,  0.19509032f,  0.38268343f,  0.55557023f,
     0.70710678f,  0.83146961f,  0.92387953f,  0.98078528f,
     1.00000000f,  0.98078528f,  0.92387953f,  0.83146961f,
     0.70710678f,  0.55557023f,  0.38268343f,  0.19509032f,
     0.00000000f, -0.19509032f, -0.38268343f, -0.55557023f,
    -0.70710678f, -0.83146961f, -0.92387953f, -0.98078528f,
    -1.00000000f, -0.98078528f, -0.92387953f, -0.83146961f,
    -0.70710678f, -0.83146961f+0.f, -0.55557023f, -0.19509032f };
// NOTE: SIN32 must be exact odd symmetry; define explicitly below instead.
constexpr float SIN32X[32] = {
     0.00000000f,  0.19509032f,  0.38268343f,  0.55557023f,
     0.70710678f,  0.83146961f,  0.92387953f,  0.98078528f,
     1.00000000f,  0.98078528f,  0.92387953f,  0.83146961f,
     0.70710678f,  0.55557023f,  0.38268343f,  0.19509032f,
     0.00000000f, -0.19509032f, -0.38268343f, -0.55557023f,
    -0.70710678f, -0.83146961f, -0.92387953f, -0.98078528f,
    -1.00000000f, -0.98078528f, -0.92387953f, -0.83146961f,
    -0.70710678f, -0.55557023f, -0.38268343f, -0.19509032f };

__device__ __forceinline__ short f2bf(float f) {
    unsigned u = __float_as_uint(f);
    u += 0x7fffu + ((u >> 16) & 1u);
    return (short)(u >> 16);
}
__device__ __forceinline__ float bf2f(unsigned short h) {
    return __uint_as_float(((unsigned)h) << 16);
}
__device__ __forceinline__ float geluf(float x) {
    // 0.5x(1+tanh(u)) == x*sigmoid(2u), 2u = 1.59577x + 0.0713548x^3
    float x2 = x * x;
    float u2 = x * fmaf(0.0713548162726f, x2, 1.59576912161f);
    float e  = __expf(-u2);
    return x * __builtin_amdgcn_rcpf(1.f + e);
}

// ------------------------------------------------ Kernel A: time-LN + scan
__global__ __launch_bounds__(128) void k_time_scan(
    const float* __restrict__ x, const float* __restrict__ dt,
    const float* __restrict__ lng, const float* __restrict__ lnb,
    const float* __restrict__ om, const float* __restrict__ bin,
    const float* __restrict__ hcr, const float* __restrict__ hci,
    const float* __restrict__ hd, float* __restrict__ buf1,
    float* __restrict__ hout)
{
    const int blk = blockIdx.x;
    const int b = blk >> 10;
    const int hw = blk & 1023;
    const int d = threadIdx.x;
    const float gd = lng[d], bd = lnb[d];
    const float omd = om[d], bind = bin[d];
    const float crd = hcr[d], cid = hci[d], dhd = hd[d];
    float hr = 0.f, hi = 0.f;
    __shared__ float red[4];
    const int wave = d >> 6;
    for (int t = 0; t < 16; ++t) {
        const size_t base = ((size_t)(b * 16 + t) * 1024 + hw) * 128;
        const float v = x[base + d];
        float s1 = v, s2 = v * v;
        #pragma unroll
        for (int o = 32; o > 0; o >>= 1) {
            s1 += __shfl_xor(s1, o);
            s2 += __shfl_xor(s2, o);
        }
        if ((d & 63) == 0) { red[wave * 2] = s1; red[wave * 2 + 1] = s2; }
        __syncthreads();
        const float mu  = (red[0] + red[2]) * (1.f / 128.f);
        const float var = (red[1] + red[3]) * (1.f / 128.f) - mu * mu;
        const float rv  = rsqrtf(var + EPSV);
        const float xt  = (v - mu) * rv * gd + bd;
        const float dtt = dt[b * 16 + t];
        float pi_, pr_;
        __sincosf(omd * dtt, &pi_, &pr_);
        const float nhr = pr_ * hr - pi_ * hi + bind * xt;
        const float nhi = pr_ * hi + pi_ * hr;
        hr = nhr; hi = nhi;
        buf1[base + d] = crd * hr - cid * hi + dhd * xt + v;
        __syncthreads();
    }
    const size_t ho = ((size_t)blk * 128 + d) * 2;
    hout[ho] = hr; hout[ho + 1] = hi;
}

// ------------------------- Kernel B: LN (+optional add / residual update) -> bf16
// pos-major in/out. grid 2048 x 256, 32 positions/block, 8 lanes/position.
__global__ __launch_bounds__(256) void k_ln(
    const float* __restrict__ add, float* __restrict__ buf1,
    const float* __restrict__ g, const float* __restrict__ b,
    unsigned short* __restrict__ xout, int update)
{
    const int tid = threadIdx.x;
    const size_t pos = (size_t)blockIdx.x * 32 + (tid >> 3);
    const int d0 = (tid & 7) << 4;
    const size_t base = pos * 128 + d0;
    float v[16];
    #pragma unroll
    for (int i = 0; i < 4; ++i) {
        float4 t = ((const float4*)(buf1 + base))[i];
        v[4*i] = t.x; v[4*i+1] = t.y; v[4*i+2] = t.z; v[4*i+3] = t.w;
    }
    if (add) {
        #pragma unroll
        for (int i = 0; i < 4; ++i) {
            float4 t = ((const float4*)(add + base))[i];
            v[4*i] += t.x; v[4*i+1] += t.y; v[4*i+2] += t.z; v[4*i+3] += t.w;
        }
    }
    float s1 = 0.f, s2 = 0.f;
    #pragma unroll
    for (int i = 0; i < 16; ++i) { s1 += v[i]; s2 += v[i] * v[i]; }
    s1 += __shfl_xor(s1, 1); s2 += __shfl_xor(s2, 1);
    s1 += __shfl_xor(s1, 2); s2 += __shfl_xor(s2, 2);
    s1 += __shfl_xor(s1, 4); s2 += __shfl_xor(s2, 4);
    const float mu = s1 * (1.f / 128.f);
    const float rv = rsqrtf(s2 * (1.f / 128.f) - mu * mu + EPSV);
    if (update) {
        #pragma unroll
        for (int i = 0; i < 4; ++i)
            ((float4*)(buf1 + base))[i] = make_float4(v[4*i], v[4*i+1], v[4*i+2], v[4*i+3]);
    }
    unsigned pk[8];
    #pragma unroll
    for (int i = 0; i < 8; ++i) {
        float a = (v[2*i]   - mu) * rv * g[d0 + 2*i]   + b[d0 + 2*i];
        float c = (v[2*i+1] - mu) * rv * g[d0 + 2*i+1] + b[d0 + 2*i+1];
        pk[i] = (unsigned)(unsigned short)f2bf(a) | ((unsigned)(unsigned short)f2bf(c) << 16);
    }
    unsigned short* p = xout + base;
    *(uint4*)p       = make_uint4(pk[0], pk[1], pk[2], pk[3]);
    *(uint4*)(p + 8) = make_uint4(pk[4], pk[5], pk[6], pk[7]);
}

// ----------------- Kernel W: pack weights into MFMA-fragment order (bf16)
// Bconv: [tap][kc][nf] frags of 1KB; W1: [kc4][nf32]; W2: [kc16][nf8]; biases f32.
__global__ __launch_bounds__(256) void k_pack(
    const float* __restrict__ cwr, const float* __restrict__ cwi,
    const float* __restrict__ cbr, const float* __restrict__ cbi,
    const float* __restrict__ w1r, const float* __restrict__ w1i,
    const float* __restrict__ b1r, const float* __restrict__ b1i,
    const float* __restrict__ w2r, const float* __restrict__ w2i,
    const float* __restrict__ b2r, const float* __restrict__ b2i,
    short* __restrict__ Bcv, short* __restrict__ W1p, short* __restrict__ W2p,
    float* __restrict__ biasc, float* __restrict__ bias1, float* __restrict__ bias2)
{
    const int idx = blockIdx.x * 256 + threadIdx.x;
    if (idx < 147456) {                       // conv frags
        const int f = idx >> 9, r = idx & 511;
        const int lane = r >> 3, j = r & 7;
        const int tap = f >> 5, kc = (f >> 3) & 3, nf = f & 7;
        const int n = nf * 16 + (lane & 15);
        const int k = kc * 32 + (lane >> 4) * 8 + j;
        const int co = n >> 1, po = n & 1, ci = k >> 1, pi = k & 1;
        const float wr = cwr[(co * 64 + ci) * 9 + tap];
        const float wi = cwi[(co * 64 + ci) * 9 + tap];
        const float val = po == 0 ? (pi == 0 ? wr : -wi) : (pi == 0 ? wi : wr);
        Bcv[idx] = f2bf(val);
    } else if (idx < 147456 + 65536) {        // W1 frags
        const int i2 = idx - 147456;
        const int f = i2 >> 9, r = i2 & 511;
        const int lane = r >> 3, j = r & 7;
        const int kc = f >> 5, nf = f & 31;
        const int n = nf * 16 + (lane & 15);          // 2e+q
        const int k = kc * 32 + (lane >> 4) * 8 + j;  // 2c+p
        const int e = n >> 1, q = n & 1, c = k >> 1, p = k & 1;
        const float ar = w1r[c * 256 + e], ai = w1i[c * 256 + e];
        const float val = q == 0 ? (p == 0 ? ar : -ai) : (p == 0 ? ai : ar);
        W1p[i2] = f2bf(val);
    } else if (idx < 147456 + 131072) {       // W2 frags
        const int i3 = idx - 147456 - 65536;
        const int f = i3 >> 9, r = i3 & 511;
        const int lane = r >> 3, j = r & 7;
        const int kc = f >> 3, nf = f & 7;
        const int n = nf * 16 + (lane & 15);          // 2co+qo
        const int k = kc * 32 + (lane >> 4) * 8 + j;  // 2e+pe
        const int co = n >> 1, qo = n & 1, e = k >> 1, pe = k & 1;
        const float ar = w2r[e * 64 + co], ai = w2i[e * 64 + co];
        const float val = qo == 0 ? (pe == 0 ? ar : -ai) : (pe == 0 ? ai : ar);
        W2p[i3] = f2bf(val);
    } else {
        const int i4 = idx - 147456 - 131072;
        if (i4 < 128)      biasc[i4] = (i4 & 1) ? cbi[i4 >> 1] : cbr[i4 >> 1];
        else if (i4 < 640) { int n = i4 - 128; bias1[n] = (n & 1) ? b1i[n >> 1] : b1r[n >> 1]; }
        else if (i4 < 768) { int n = i4 - 640; bias2[n] = (n & 1) ? b2i[n >> 1] : b2r[n >> 1]; }
    }
}

// --------------------------- Kernel C: precompute K = U@V and mod = exp(lam*dt)
__global__ __launch_bounds__(256) void k_pre(
    const float* __restrict__ ur, const float* __restrict__ ui,
    const float* __restrict__ vr, const float* __restrict__ vi,
    const float* __restrict__ dec, const float* __restrict__ om,
    const float* __restrict__ dt, float* __restrict__ Kb, float* __restrict__ Mb)
{
    const int id = blockIdx.x * 256 + threadIdx.x;
    if (id < 128 * 17) {
        const int d = id / 17, f = id % 17;
        float ar = 0.f, ai = 0.f;
        for (int r = 0; r < 32; ++r) {
            const float a = ur[d * 32 + r], b = ui[d * 32 + r];
            const float c = vr[r * 17 + f], e = vi[r * 17 + f];
            ar += a * c - b * e;
            ai += a * e + b * c;
        }
        Kb[id * 2] = ar; Kb[id * 2 + 1] = ai;
    } else if (id < 128 * 17 + 64 * 17) {
        const int m = id - 128 * 17;
        const int n = m / 17, f = m % 17;
        const float xv = dec[f];
        const float sp = (xv > 20.f) ? xv : log1pf(expf(xv));
        const float dtv = dt[n];
        const float mag = expf(-sp * dtv);
        float s, c; __sincosf(om[f] * dtv, &s, &c);
        Mb[m * 2] = mag * c; Mb[m * 2 + 1] = mag * s;
    }
}

// ------------------------------ Kernel D: implicit-GEMM complex conv (MFMA)
// grid 512 (n = blk>>3, hq = blk&7), 256 threads = 4 waves (2M x 2N).
// A tile in LDS: 6 hrows x 34 w x 128 feats bf16, swizzled. B frag-packed in L2.
__global__ __launch_bounds__(256) void k_conv(
    const unsigned short* __restrict__ xnb, const short* __restrict__ Bcv,
    const float* __restrict__ biasc, float* __restrict__ convout)
{
    __shared__ char As[52224];   // 204 pos * 256B
    const int tid = threadIdx.x;
    const int lane = tid & 63, wid = tid >> 6;
    const int wm = wid >> 1, wn = wid & 1;
    const int n = blockIdx.x >> 3, hq = blockIdx.x & 7;
    const int h0 = hq * 4;
    // stage halo tile
    for (int i = tid; i < 3264; i += 256) {
        const int p = i >> 4, seg = i & 15;
        const int hr = p / 34, wp = p - hr * 34;
        const int hh = h0 + hr - 1, ww = wp - 1;
        uint4 val = make_uint4(0u, 0u, 0u, 0u);
        if (hh >= 0 && hh < 32 && ww >= 0 && ww < 32)
            val = *(const uint4*)(xnb + ((size_t)((n * 32 + hh) * 32 + ww) * 128 + seg * 8));
        int byt = (p << 8) + (seg << 4);
        byt ^= (p & 7) << 4;
        *(uint4*)(As + byt) = val;
    }
    __syncthreads();

    int posb[4];
    #pragma unroll
    for (int fm = 0; fm < 4; ++fm) {
        const int m = wm * 64 + fm * 16 + (lane & 15);
        posb[fm] = (m >> 5) * 34 + (m & 31);
    }
    const int kob = (lane >> 4) << 4;   // k-offset bytes within kc-chunk
    const char* bbase = (const char*)Bcv + (lane << 4);

    fx4 acc[4][4];
    #pragma unroll
    for (int a = 0; a < 4; ++a)
        #pragma unroll
        for (int b = 0; b < 4; ++b) acc[a][b] = (fx4){0.f, 0.f, 0.f, 0.f};

    for (int tap = 0; tap < 9; ++tap) {
        const int ty = (tap * 11) >> 5;
        const int tx = tap - ty * 3;
        const int shift = ty * 34 + tx;
        #pragma unroll
        for (int kc = 0; kc < 4; ++kc) {
            bfx8 af[4], bf_[4];
            #pragma unroll
            for (int fm = 0; fm < 4; ++fm) {
                const int pos = posb[fm] + shift;
                int byt = (pos << 8) + (kc << 6) + kob;
                byt ^= (pos & 7) << 4;
                af[fm] = *(const bfx8*)(As + byt);
            }
            #pragma unroll
            for (int fn = 0; fn < 4; ++fn)
                bf_[fn] = *(const bfx8*)(bbase + (((tap * 4 + kc) * 8 + wn * 4 + fn) << 10));
            #pragma unroll
            for (int fm = 0; fm < 4; ++fm)
                #pragma unroll
                for (int fn = 0; fn < 4; ++fn)
                    acc[fm][fn] = __builtin_amdgcn_mfma_f32_16x16x32_bf16(af[fm], bf_[fn], acc[fm][fn], 0, 0, 0);
        }
    }
    // epilogue: bias + store position-major f32
    const int pbase = (n * 8 + hq) * 128;
    #pragma unroll
    for (int fn = 0; fn < 4; ++fn) {
        const int col = wn * 64 + fn * 16 + (lane & 15);
        const float bc = biasc[col];
        #pragma unroll
        for (int fm = 0; fm < 4; ++fm) {
            const int r0 = wm * 64 + fm * 16 + ((lane >> 4) << 2);
            #pragma unroll
            for (int j = 0; j < 4; ++j)
                convout[(size_t)(pbase + r0 + j) * 128 + col] = acc[fm][fn][j] + bc;
        }
    }
}

// ----------------- Kernel E: spectral mix (DFT along w), accumulates into convout
// grid 2048 (n = blk>>5, h = blk&31), 128 threads.
__global__ __launch_bounds__(128) void k_spec(
    const unsigned short* __restrict__ xnb, const float* __restrict__ Kb,
    const float* __restrict__ Mb, float* __restrict__ convout)
{
    __shared__ float lds[128][33];
    const int tid = threadIdx.x;
    const int n = blockIdx.x >> 5, h = blockIdx.x & 31;
    const size_t rowbase = (size_t)((n * 32 + h) * 32) * 128;
    for (int i = tid; i < 512; i += 128) {
        const int w = i >> 4, seg = i & 15;
        uint4 t = *(const uint4*)(xnb + rowbase + (size_t)w * 128 + seg * 8);
        const unsigned u[4] = {t.x, t.y, t.z, t.w};
        #pragma unroll
        for (int q = 0; q < 4; ++q) {
            lds[seg * 8 + 2 * q][w]     = bf2f((unsigned short)(u[q] & 0xffffu));
            lds[seg * 8 + 2 * q + 1][w] = bf2f((unsigned short)(u[q] >> 16));
        }
    }
    __syncthreads();
    const int d = tid;
    float xv[32];
    #pragma unroll
    for (int w = 0; w < 32; ++w) xv[w] = lds[d][w];
    float zr[17], zi[17];
    #pragma unroll
    for (int f = 0; f < 17; ++f) {
        float sr = 0.f, si = 0.f;
        #pragma unroll
        for (int w2 = 0; w2 < 32; ++w2) {
            sr += xv[w2] * COS32[(f * w2) & 31];
            si -= xv[w2] * SIN32X[(f * w2) & 31];
        }
        const float kr = Kb[(d * 17 + f) * 2], ki = Kb[(d * 17 + f) * 2 + 1];
        const float mr = Mb[(n * 17 + f) * 2], mi = Mb[(n * 17 + f) * 2 + 1];
        const float cr2 = kr * mr - ki * mi;
        const float ci2 = kr * mi + ki * mr;
        zr[f] = sr * cr2 - si * ci2;
        zi[f] = sr * ci2 + si * cr2;
    }
    #pragma unroll
    for (int w2 = 0; w2 < 32; ++w2) {
        float acc = zr[0] + ((w2 & 1) ? -zr[16] : zr[16]);
        #pragma unroll
        for (int f = 1; f < 16; ++f)
            acc += 2.f * (zr[f] * COS32[(f * w2) & 31] - zi[f] * SIN32X[(f * w2) & 31]);
        lds[d][w2] = acc * (1.f / 32.f);
    }
    __syncthreads();
    for (int i = tid; i < 512; i += 128) {
        const int w = i >> 4, seg = i & 15;
        float* dst = convout + rowbase + (size_t)w * 128 + seg * 8;
        float4 c0 = *(const float4*)dst;
        float4 c1 = *(const float4*)(dst + 4);
        c0.x += lds[seg * 8 + 0][w]; c0.y += lds[seg * 8 + 1][w];
        c0.z += lds[seg * 8 + 2][w]; c0.w += lds[seg * 8 + 3][w];
        c1.x += lds[seg * 8 + 4][w]; c1.y += lds[seg * 8 + 5][w];
        c1.z += lds[seg * 8 + 6][w]; c1.w += lds[seg * 8 + 7][w];
        *(float4*)dst = c0;
        *(float4*)(dst + 4) = c1;
    }
}

// ------------------------------ Kernel G: fused complex MLP via MFMA
// grid 2048 (32 positions/block), 256 threads = 4 waves.
__global__ __launch_bounds__(256) void k_mlp(
    const unsigned short* __restrict__ xnb, const float* __restrict__ res,
    const short* __restrict__ W1p, const short* __restrict__ W2p,
    const float* __restrict__ bias1, const float* __restrict__ bias2,
    float* __restrict__ outp)
{
    __shared__ char Xs[8192];    // 32 x 256B
    __shared__ char Hs[32768];   // 32 x 1024B
    const int tid = threadIdx.x;
    const int lane = tid & 63, wid = tid >> 6;
    const int blk = blockIdx.x;
    for (int i = tid; i < 512; i += 256) {
        const int m = i >> 4, seg = i & 15;
        uint4 v = *(const uint4*)(xnb + ((size_t)(blk * 32 + m) * 128 + seg * 8));
        int byt = (m << 8) + (seg << 4);
        byt ^= (m & 7) << 4;
        *(uint4*)(Xs + byt) = v;
    }
    __syncthreads();
    const int kob = (lane >> 4) << 4;
    const char* w1base = (const char*)W1p + (lane << 4);
    const char* w2base = (const char*)W2p + (lane << 4);

    fx4 a1[2][8];
    #pragma unroll
    for (int a = 0; a < 2; ++a)
        #pragma unroll
        for (int b = 0; b < 8; ++b) a1[a][b] = (fx4){0.f, 0.f, 0.f, 0.f};
    #pragma unroll
    for (int kc = 0; kc < 4; ++kc) {
        bfx8 xa[2], wb[8];
        #pragma unroll
        for (int fm = 0; fm < 2; ++fm) {
            const int r = fm * 16 + (lane & 15);
            int byt = (r << 8) + (kc << 6) + kob;
            byt ^= (r & 7) << 4;
            xa[fm] = *(const bfx8*)(Xs + byt);
        }
        #pragma unroll
        for (int fn = 0; fn < 8; ++fn)
            wb[fn] = *(const bfx8*)(w1base + (((kc * 32 + wid * 8 + fn)) << 10));
        #pragma unroll
        for (int fm = 0; fm < 2; ++fm)
            #pragma unroll
            for (int fn = 0; fn < 8; ++fn)
                a1[fm][fn] = __builtin_amdgcn_mfma_f32_16x16x32_bf16(xa[fm], wb[fn], a1[fm][fn], 0, 0, 0);
    }
    // bias + gelu -> Hs (bf16)
    #pragma unroll
    for (int fn = 0; fn < 8; ++fn) {
        const int c = wid * 128 + fn * 16 + (lane & 15);
        const float bv = bias1[c];
        #pragma unroll
        for (int fm = 0; fm < 2; ++fm) {
            #pragma unroll
            for (int j = 0; j < 4; ++j) {
                const int r = fm * 16 + ((lane >> 4) << 2) + j;
                const float g = geluf(a1[fm][fn][j] + bv);
                int byt = (r << 10) + (c << 1);
                byt ^= (r & 7) << 4;
                *(short*)(Hs + byt) = f2bf(g);
            }
        }
    }
    __syncthreads();
    fx4 a2[2][2];
    #pragma unroll
    for (int a = 0; a < 2; ++a)
        #pragma unroll
        for (int b = 0; b < 2; ++b) a2[a][b] = (fx4){0.f, 0.f, 0.f, 0.f};
    #pragma unroll
    for (int kc = 0; kc < 16; ++kc) {
        bfx8 ha[2], wb[2];
        #pragma unroll
        for (int fm = 0; fm < 2; ++fm) {
            const int r = fm * 16 + (lane & 15);
            int byt = (r << 10) + (kc << 6) + kob;
            byt ^= (r & 7) << 4;
            ha[fm] = *(const bfx8*)(Hs + byt);
        }
        #pragma unroll
        for (int fn = 0; fn < 2; ++fn)
            wb[fn] = *(const bfx8*)(w2base + ((kc * 8 + wid * 2 + fn) << 10));
        #pragma unroll
        for (int fm = 0; fm < 2; ++fm)
            #pragma unroll
            for (int fn = 0; fn < 2; ++fn)
                a2[fm][fn] = __builtin_amdgcn_mfma_f32_16x16x32_bf16(ha[fm], wb[fn], a2[fm][fn], 0, 0, 0);
    }
    #pragma unroll
    for (int fn = 0; fn < 2; ++fn) {
        const int col = wid * 32 + fn * 16 + (lane & 15);
        const float bv = bias2[col];
        #pragma unroll
        for (int fm = 0; fm < 2; ++fm) {
            const int r0 = fm * 16 + ((lane >> 4) << 2);
            #pragma unroll
            for (int j = 0; j < 4; ++j) {
                const size_t o = (size_t)(blk * 32 + r0 + j) * 128 + col;
                outp[o] = a2[fm][fn][j] + bv + res[o];
            }
        }
    }
}

extern "C" void kernel_launch(void* const* d_in, const int* in_sizes, int n_in,
                              void* d_out, int out_size, void* d_ws, size_t ws_size,
                              hipStream_t stream) {
    const float* x          = (const float*)d_in[0];
    const float* dt         = (const float*)d_in[1];
    const float* ln_time_g  = (const float*)d_in[2];
    const float* ln_time_b  = (const float*)d_in[3];
    const float* ln_space_g = (const float*)d_in[4];
    const float* ln_space_b = (const float*)d_in[5];
    const float* ln_feat_g  = (const float*)d_in[6];
    const float* ln_feat_b  = (const float*)d_in[7];
    const float* ham_omega  = (const float*)d_in[8];
    const float* ham_bin    = (const float*)d_in[9];
    const float* ham_cr     = (const float*)d_in[10];
    const float* ham_ci     = (const float*)d_in[11];
    const float* ham_d      = (const float*)d_in[12];
    const float* cliff_wr   = (const float*)d_in[13];
    const float* cliff_wi   = (const float*)d_in[14];
    const float* cliff_br   = (const float*)d_in[15];
    const float* cliff_bi   = (const float*)d_in[16];
    const float* spec_ur    = (const float*)d_in[17];
    const float* spec_ui    = (const float*)d_in[18];
    const float* spec_vr    = (const float*)d_in[19];
    const float* spec_vi    = (const float*)d_in[20];
    const float* spec_decay = (const float*)d_in[21];
    const float* spec_omega = (const float*)d_in[22];
    const float* w1r        = (const float*)d_in[23];
    const float* w1i        = (const float*)d_in[24];
    const float* b1r        = (const float*)d_in[25];
    const float* b1i        = (const float*)d_in[26];
    const float* w2r        = (const float*)d_in[27];
    const float* w2i        = (const float*)d_in[28];
    const float* b2r        = (const float*)d_in[29];
    const float* b2i        = (const float*)d_in[30];

    float* out = (float*)d_out;
    const size_t NX = 8388608;               // B*T*H*W*C*2
    float* hout    = out + NX;
    float* convout = out;                    // scratch until k_mlp rewrites

    float* ws = (float*)d_ws;
    float* buf1 = ws;                                          // 8388608 f32
    unsigned short* xnb = (unsigned short*)(ws + 8388608);     // 8388608 bf16
    short* Bcv  = (short*)(ws + 12582912);                     // 147456 bf16
    short* W1p  = (short*)(ws + 12656640);                     // 65536 bf16
    short* W2p  = (short*)(ws + 12689408);                     // 65536 bf16
    float* biasc = ws + 12722176;                              // 128
    float* bias1 = ws + 12722304;                              // 512
    float* bias2 = ws + 12722816;                              // 128
    float* Kb    = ws + 12722944;                              // 4352
    float* Mb    = ws + 12727296;                              // 2176

    k_pack<<<1091, 256, 0, stream>>>(cliff_wr, cliff_wi, cliff_br, cliff_bi,
                                     w1r, w1i, b1r, b1i, w2r, w2i, b2r, b2i,
                                     Bcv, W1p, W2p, biasc, bias1, bias2);
    k_pre<<<13, 256, 0, stream>>>(spec_ur, spec_ui, spec_vr, spec_vi,
                                  spec_decay, spec_omega, dt, Kb, Mb);
    k_time_scan<<<4096, 128, 0, stream>>>(x, dt, ln_time_g, ln_time_b,
                                          ham_omega, ham_bin, ham_cr, ham_ci,
                                          ham_d, buf1, hout);
    k_ln<<<2048, 256, 0, stream>>>(nullptr, buf1, ln_space_g, ln_space_b, xnb, 0);
    k_conv<<<512, 256, 0, stream>>>(xnb, Bcv, biasc, convout);
    k_spec<<<2048, 128, 0, stream>>>(xnb, Kb, Mb, convout);
    k_ln<<<2048, 256, 0, stream>>>(convout, buf1, ln_feat_g, ln_feat_b, xnb, 1);
    k_mlp<<<2048, 256, 0, stream>>>(xnb, buf1, W1p, W2p, bias1, bias2, out);
}